// Round 2
// baseline (118.108 us; speedup 1.0000x reference)
//
#include <hip/hip_runtime.h>
#include <hip/hip_fp16.h>

#define CDIM 512
#define NDIM 512
#define PF   4          // prefetch depth (steps of 2KB)

typedef _Float16 half8  __attribute__((ext_vector_type(8)));
typedef float    f32x16 __attribute__((ext_vector_type(16)));

// ---------------- K1a: v[j] = relu(Q . Wq[j,:] + bq[j]) * Wout[j/64] / 8 ----------------
__global__ void qproj_kernel(const float* __restrict__ Q, const float* __restrict__ Wq,
                             const float* __restrict__ bq, const float* __restrict__ Wout,
                             float* __restrict__ v) {
    __shared__ float qs[CDIM];
    const int t = threadIdx.x;
    for (int i = t; i < CDIM; i += 64) qs[i] = Q[i];
    __syncthreads();
    const int j = blockIdx.x * 64 + t;
    const float4* w4 = (const float4*)(Wq + (size_t)j * CDIM);
    const float4* q4 = (const float4*)qs;
    float s = 0.f;
    #pragma unroll 8
    for (int i = 0; i < CDIM / 4; ++i) {
        float4 w = w4[i]; float4 q = q4[i];
        s = fmaf(w.x, q.x, s); s = fmaf(w.y, q.y, s);
        s = fmaf(w.z, q.z, s); s = fmaf(w.w, q.w, s);
    }
    s += bq[j];
    s = fmaxf(s, 0.f);
    v[j] = s * Wout[j >> 6] * 0.125f;   // 1/sqrt(64) folded; bout dropped (softmax shift-invariant)
}

// ---------------- K1b: Wk fp32 -> fp16 in MFMA-B-fragment-major layout ----------------
// Stream layout: step s (= jt*32 + kc) -> 2KB block: [frag(jblock 2*jt) 1KB][frag(2*jt+1) 1KB].
// Within a 1KB frag, lane l holds 8 fp16: B[k = kc*16 + (l>>5)*8 + 0..7][j = jb*32 + (l&31)].
__global__ void wkfrag_kernel(const float* __restrict__ Wk, _Float16* __restrict__ Wkf) {
    const int gid  = blockIdx.x * 256 + threadIdx.x;   // one half8 each, 32768 total
    const int s    = gid >> 7;
    const int half = (gid >> 6) & 1;
    const int l    = gid & 63;
    const int jt   = s >> 5;
    const int kc   = s & 31;
    const int j    = (2 * jt + half) * 32 + (l & 31);
    const int k    = kc * 16 + (l >> 5) * 8;
    const float* src = Wk + (size_t)j * CDIM + k;
    float4 f0 = *(const float4*)(src);
    float4 f1 = *(const float4*)(src + 4);
    half8 h;
    h[0]=(_Float16)f0.x; h[1]=(_Float16)f0.y; h[2]=(_Float16)f0.z; h[3]=(_Float16)f0.w;
    h[4]=(_Float16)f1.x; h[5]=(_Float16)f1.y; h[6]=(_Float16)f1.z; h[7]=(_Float16)f1.w;
    *(half8*)(Wkf + (size_t)gid * 8) = h;
}

// ---------------- K2: logits[t] = sum_j v[j] * relu(K[t,:] . Wk[j,:] + bk[j]) ----------------
// One wave per block, 32 rows per wave, A (K rows, full depth 512) in registers.
// Wk fragments streamed linearly from L2 (no LDS, no barriers), prefetch depth PF.
__global__ __launch_bounds__(64, 2) void score_kernel(
    const float* __restrict__ Kmat, const _Float16* __restrict__ Wkf,
    const float* __restrict__ bk, const float* __restrict__ v,
    float* __restrict__ logits)
{
    const int lane = threadIdx.x;
    const int l31  = lane & 31;
    const int lhi  = lane >> 5;
    const int row  = blockIdx.x * 32 + l31;

    // ---- A prologue: 32 half8 fragments (full depth 512), fp32 -> fp16 ----
    half8 a[32];
    const float* abase = Kmat + (size_t)row * CDIM + lhi * 8;
    #pragma unroll
    for (int kt = 0; kt < 32; ++kt) {
        float4 f0 = *(const float4*)(abase + kt * 16);
        float4 f1 = *(const float4*)(abase + kt * 16 + 4);
        half8 h;
        h[0]=(_Float16)f0.x; h[1]=(_Float16)f0.y; h[2]=(_Float16)f0.z; h[3]=(_Float16)f0.w;
        h[4]=(_Float16)f1.x; h[5]=(_Float16)f1.y; h[6]=(_Float16)f1.z; h[7]=(_Float16)f1.w;
        a[kt] = h;
    }

    const char* bbase = (const char*)Wkf + lane * 16;

    // prime prefetch pipeline (steps 0..PF-1)
    half8 pb0[PF], pb1[PF];
    #pragma unroll
    for (int p = 0; p < PF; ++p) {
        pb0[p] = *(const half8*)(bbase + (size_t)p * 2048);
        pb1[p] = *(const half8*)(bbase + (size_t)p * 2048 + 1024);
    }

    float part[16];
    #pragma unroll
    for (int r = 0; r < 16; ++r) part[r] = 0.f;

    for (int jt = 0; jt < 8; ++jt) {
        f32x16 acc0, acc1;
        #pragma unroll
        for (int r = 0; r < 16; ++r) { acc0[r] = 0.f; acc1[r] = 0.f; }

        #pragma unroll
        for (int kq = 0; kq < 32; ++kq) {
            const int pi = kq & (PF - 1);
            half8 b0 = pb0[pi];
            half8 b1 = pb1[pi];
            // prefetch step s+PF (linear stream; tail over-read stays inside ws)
            {
                const char* np = bbase + (size_t)jt * 65536 + (size_t)(kq + PF) * 2048;
                pb0[pi] = *(const half8*)(np);
                pb1[pi] = *(const half8*)(np + 1024);
            }
            acc0 = __builtin_amdgcn_mfma_f32_32x32x16_f16(a[kq], b0, acc0, 0, 0, 0);
            acc1 = __builtin_amdgcn_mfma_f32_32x32x16_f16(a[kq], b1, acc1, 0, 0, 0);
        }

        // depth complete for this j-tile: bias + relu + v-weighted reduce
        const int j0 = jt * 64 + l31;
        const float bj0 = bk[j0];       const float vj0 = v[j0];
        const float bj1 = bk[j0 + 32];  const float vj1 = v[j0 + 32];
        #pragma unroll
        for (int r = 0; r < 16; ++r) {
            float v0 = fmaxf(acc0[r] + bj0, 0.f);
            float v1 = fmaxf(acc1[r] + bj1, 0.f);
            part[r] = fmaf(v0, vj0, part[r]);
            part[r] = fmaf(v1, vj1, part[r]);
        }
    }

    // reduce over the 32 j-columns (lanes sharing lhi); C layout: col=lane&31, row=(r&3)+8*(r>>2)+4*lhi
    #pragma unroll
    for (int r = 0; r < 16; ++r) {
        float s = part[r];
        s += __shfl_xor(s, 1);
        s += __shfl_xor(s, 2);
        s += __shfl_xor(s, 4);
        s += __shfl_xor(s, 8);
        s += __shfl_xor(s, 16);
        if (l31 == 0) {
            const int rrow = (r & 3) + 8 * (r >> 2) + 4 * lhi;
            logits[blockIdx.x * 32 + rrow] = s;
        }
    }
}

// ---------------- K3: deterministic per-block exp-sum (256 blocks x 256) ----------------
__global__ void expsum_kernel(const float* __restrict__ logits, float* __restrict__ partial) {
    __shared__ float red[256];
    const int t = threadIdx.x;
    red[t] = expf(logits[blockIdx.x * 256 + t]);
    __syncthreads();
    for (int s = 128; s > 0; s >>= 1) {
        if (t < s) red[t] += red[t + s];
        __syncthreads();
    }
    if (t == 0) partial[blockIdx.x] = red[0];
}

// ---------------- K4: normalize ----------------
__global__ void norm_kernel(const float* __restrict__ logits, const float* __restrict__ partial,
                            float* __restrict__ out) {
    __shared__ float red[256];
    const int t = threadIdx.x;
    red[t] = partial[t];
    __syncthreads();
    for (int s = 128; s > 0; s >>= 1) {
        if (t < s) red[t] += red[t + s];
        __syncthreads();
    }
    const float zinv = 1.0f / red[0];
    const int i = blockIdx.x * 256 + t;
    out[i] = expf(logits[i]) * zinv;
}

extern "C" void kernel_launch(void* const* d_in, const int* in_sizes, int n_in,
                              void* d_out, int out_size, void* d_ws, size_t ws_size,
                              hipStream_t stream) {
    const float* Q    = (const float*)d_in[0];
    const float* Kmat = (const float*)d_in[1];
    const float* Wq   = (const float*)d_in[2];
    const float* bq   = (const float*)d_in[3];
    const float* Wk   = (const float*)d_in[4];
    const float* bk   = (const float*)d_in[5];
    const float* Wout = (const float*)d_in[6];
    float* out = (float*)d_out;

    char* ws = (char*)d_ws;
    _Float16* Wkf  = (_Float16*)(ws);                 // 512*512*2 = 524288 B (+ tail over-read pad)
    float* v       = (float*)(ws + 524288);           // 2048 B
    float* logits  = (float*)(ws + 526336);           // 262144 B
    float* partial = (float*)(ws + 788480);           // 1024 B

    hipLaunchKernelGGL(qproj_kernel,  dim3(8),    dim3(64),  0, stream, Q, Wq, bq, Wout, v);
    hipLaunchKernelGGL(wkfrag_kernel, dim3(128),  dim3(256), 0, stream, Wk, Wkf);
    hipLaunchKernelGGL(score_kernel,  dim3(2048), dim3(64),  0, stream, Kmat, Wkf, bk, v, logits);
    hipLaunchKernelGGL(expsum_kernel, dim3(256),  dim3(256), 0, stream, logits, partial);
    hipLaunchKernelGGL(norm_kernel,   dim3(256),  dim3(256), 0, stream, logits, partial, out);
}

// Round 3
// 75.916 us; speedup vs baseline: 1.5558x; 1.5558x over previous
//
#include <hip/hip_runtime.h>
#include <hip/hip_fp16.h>

#define CDIM  512
#define ROWS  65536
#define NWG   128      // WGs per j-class
#define TILES 16       // 32-row tiles per WG: NWG*32*TILES = ROWS

typedef _Float16 half8  __attribute__((ext_vector_type(8)));
typedef _Float16 half4t __attribute__((ext_vector_type(4)));
typedef float    f32x16 __attribute__((ext_vector_type(16)));

// ---------------- K1a: v[j] = relu(Q . Wq[j,:] + bq[j]) * Wout[j/64] / 8 ----------------
// 32 blocks x 256 thr; 16 threads per j, 16 j per block.
__global__ void qproj_kernel(const float* __restrict__ Q, const float* __restrict__ Wq,
                             const float* __restrict__ bq, const float* __restrict__ Wout,
                             float* __restrict__ v) {
    __shared__ float qs[CDIM];
    const int t = threadIdx.x;
    qs[t] = Q[t]; qs[t + 256] = Q[t + 256];
    __syncthreads();
    const int jj  = t >> 4;
    const int sub = t & 15;
    const int j   = blockIdx.x * 16 + jj;
    const float4* w4 = (const float4*)(Wq + (size_t)j * CDIM + sub * 32);
    const float4* q4 = (const float4*)(qs + sub * 32);
    float s = 0.f;
    #pragma unroll
    for (int i = 0; i < 8; ++i) {
        float4 w = w4[i]; float4 q = q4[i];
        s = fmaf(w.x, q.x, s); s = fmaf(w.y, q.y, s);
        s = fmaf(w.z, q.z, s); s = fmaf(w.w, q.w, s);
    }
    s += __shfl_xor(s, 1); s += __shfl_xor(s, 2);
    s += __shfl_xor(s, 4); s += __shfl_xor(s, 8);
    if (sub == 0) {
        s += bq[j];
        s = fmaxf(s, 0.f);
        v[j] = s * Wout[j >> 6] * 0.125f;   // 1/sqrt(64) folded; bout dropped (shift-invariant)
    }
}

// ---------------- K1b: Wk -> fp16 B-fragments [jb 0..15][kc 0..31][lane 0..63][8 halfs] ----
// Fragment (jb,kc), lane l: B[k = kc*16 + (l>>5)*8 + e][j = jb*32 + (l&31)]
__global__ void wkfrag_kernel(const float* __restrict__ Wk, _Float16* __restrict__ Wkf) {
    const int gid = blockIdx.x * 256 + threadIdx.x;   // 32768 half8 slots
    const int jb  = gid >> 11;
    const int kc  = (gid >> 6) & 31;
    const int l   = gid & 63;
    const int j   = jb * 32 + (l & 31);
    const int k   = kc * 16 + (l >> 5) * 8;
    const float* src = Wk + (size_t)j * CDIM + k;
    float4 f0 = *(const float4*)(src);
    float4 f1 = *(const float4*)(src + 4);
    half8 h;
    h[0]=(_Float16)f0.x; h[1]=(_Float16)f0.y; h[2]=(_Float16)f0.z; h[3]=(_Float16)f0.w;
    h[4]=(_Float16)f1.x; h[5]=(_Float16)f1.y; h[6]=(_Float16)f1.z; h[7]=(_Float16)f1.w;
    *(half8*)(Wkf + (size_t)gid * 8) = h;
}

// ---------------- K2: Wk-resident score kernel ----------------
// grid (NWG, 2): class c owns j in [c*256, c*256+256); 8 waves x 32 j each (B in 128 VGPRs).
// K rows streamed once through LDS (fp32->fp16 at staging, A-fragment-major, rotate-swizzled).
__global__ __launch_bounds__(512, 2) void score_kernel(
    const float* __restrict__ Kmat, const _Float16* __restrict__ Wkf,
    const float* __restrict__ bk, const float* __restrict__ v,
    float* __restrict__ partial2)
{
    __shared__ alignas(16) char stage[2][32768];   // 2 x (32 rows x 512 k fp16, frag-major)
    __shared__ float scratch[2][8][32];            // per-tile cross-wave row partials

    const int tid  = threadIdx.x;
    const int lane = tid & 63;
    const int wave = tid >> 6;
    const int l31  = lane & 31;
    const int lhi  = lane >> 5;
    const int cls  = blockIdx.y;
    const int jb   = cls * 8 + wave;

    // ---- B prologue: 32 resident fragments (full depth for this wave's 32 j's) ----
    half8 B[32];
    const half8* bsrc = (const half8*)Wkf + ((size_t)jb * 32) * 64 + lane;
    #pragma unroll
    for (int kc = 0; kc < 32; ++kc) B[kc] = bsrc[kc * 64];
    const int jmy = jb * 32 + l31;
    const float bj = bk[jmy];
    const float vj = v[jmy];

    const int rowbase0 = blockIdx.x * (TILES * 32);
    float* pbase = partial2 + (size_t)cls * ROWS;

    // staging geometry (per thread, constant): w = tid&127 -> 16B of a row
    const int sw  = tid & 127;
    const int skc = sw >> 2;
    const int skh = (sw >> 1) & 1;
    const int spr = sw & 1;
    const int srow_off = tid >> 7;                 // 0..3; row = it*4 + srow_off

    // ---- prologue: stage tile 0 ----
    #pragma unroll
    for (int it = 0; it < 8; ++it) {
        const int row = it * 4 + srow_off;
        float4 g = *(const float4*)(Kmat + (size_t)(rowbase0 + row) * CDIM + sw * 4);
        half4t h = {(_Float16)g.x, (_Float16)g.y, (_Float16)g.z, (_Float16)g.w};
        const int off = skc * 1024 + (((row + 32 * skh + skc) & 63) * 16) + spr * 8;
        *(half4t*)(&stage[0][off]) = h;
    }
    __syncthreads();

    for (int t = 0; t < TILES; ++t) {
        const int cur = t & 1;
        const bool pf = (t + 1 < TILES);

        // issue-early: global loads for tile t+1 (held in regs; written after compute)
        float4 g[8];
        if (pf) {
            const int rs = rowbase0 + (t + 1) * 32;
            #pragma unroll
            for (int it = 0; it < 8; ++it)
                g[it] = *(const float4*)(Kmat + (size_t)(rs + it * 4 + srow_off) * CDIM + sw * 4);
        }

        // cross-wave summer for tile t-1 (wave 0 only)
        if (t > 0 && tid < 32) {
            float s = 0.f;
            #pragma unroll
            for (int w = 0; w < 8; ++w) s += scratch[(t - 1) & 1][w][tid];
            pbase[rowbase0 + (t - 1) * 32 + tid] = s;
        }

        // ---- compute: 32 chunks, 2 independent MFMA chains ----
        f32x16 acc0, acc1;
        #pragma unroll
        for (int r = 0; r < 16; ++r) { acc0[r] = 0.f; acc1[r] = 0.f; }
        #pragma unroll
        for (int kc = 0; kc < 32; kc += 2) {
            half8 a0 = *(const half8*)(&stage[cur][kc * 1024 + ((lane + kc) & 63) * 16]);
            half8 a1 = *(const half8*)(&stage[cur][(kc + 1) * 1024 + ((lane + kc + 1) & 63) * 16]);
            acc0 = __builtin_amdgcn_mfma_f32_32x32x16_f16(a0, B[kc],     acc0, 0, 0, 0);
            acc1 = __builtin_amdgcn_mfma_f32_32x32x16_f16(a1, B[kc + 1], acc1, 0, 0, 0);
        }

        // ---- epilogue: relu + v-weight, reduce over the 32 j-lanes ----
        float part[16];
        #pragma unroll
        for (int r = 0; r < 16; ++r) {
            float x = fmaxf(acc0[r] + acc1[r] + bj, 0.f) * vj;
            x += __shfl_xor(x, 1);
            x += __shfl_xor(x, 2);
            x += __shfl_xor(x, 4);
            x += __shfl_xor(x, 8);
            x += __shfl_xor(x, 16);
            part[r] = x;
        }
        if (l31 == 0) {
            #pragma unroll
            for (int r = 0; r < 16; ++r)
                scratch[cur][wave][(r & 3) + 8 * (r >> 2) + 4 * lhi] = part[r];
        }

        // write-late: staged regs -> other buffer
        if (pf) {
            #pragma unroll
            for (int it = 0; it < 8; ++it) {
                const int row = it * 4 + srow_off;
                half4t h = {(_Float16)g[it].x, (_Float16)g[it].y, (_Float16)g[it].z, (_Float16)g[it].w};
                const int off = skc * 1024 + (((row + 32 * skh + skc) & 63) * 16) + spr * 8;
                *(half4t*)(&stage[cur ^ 1][off]) = h;
            }
        }
        __syncthreads();
    }

    // drain: summer for the last tile
    if (tid < 32) {
        float s = 0.f;
        #pragma unroll
        for (int w = 0; w < 8; ++w) s += scratch[(TILES - 1) & 1][w][tid];
        pbase[rowbase0 + (TILES - 1) * 32 + tid] = s;
    }
}

// ---------------- K3: merge classes, store logits, per-block exp-sum ----------------
__global__ void expsum_kernel(const float* __restrict__ partial2, float* __restrict__ logits,
                              float* __restrict__ blocksum) {
    __shared__ float red[256];
    const int t = threadIdx.x;
    const int row = blockIdx.x * 256 + t;
    const float lg = partial2[row] + partial2[ROWS + row];
    logits[row] = lg;
    red[t] = expf(lg);
    __syncthreads();
    for (int s = 128; s > 0; s >>= 1) {
        if (t < s) red[t] += red[t + s];
        __syncthreads();
    }
    if (t == 0) blocksum[blockIdx.x] = red[0];
}

// ---------------- K4: normalize ----------------
__global__ void norm_kernel(const float* __restrict__ logits, const float* __restrict__ blocksum,
                            float* __restrict__ out) {
    __shared__ float red[256];
    const int t = threadIdx.x;
    red[t] = blocksum[t];
    __syncthreads();
    for (int s = 128; s > 0; s >>= 1) {
        if (t < s) red[t] += red[t + s];
        __syncthreads();
    }
    const float zinv = 1.0f / red[0];
    const int i = blockIdx.x * 256 + t;
    out[i] = expf(logits[i]) * zinv;
}

extern "C" void kernel_launch(void* const* d_in, const int* in_sizes, int n_in,
                              void* d_out, int out_size, void* d_ws, size_t ws_size,
                              hipStream_t stream) {
    const float* Q    = (const float*)d_in[0];
    const float* Kmat = (const float*)d_in[1];
    const float* Wq   = (const float*)d_in[2];
    const float* bq   = (const float*)d_in[3];
    const float* Wk   = (const float*)d_in[4];
    const float* bk   = (const float*)d_in[5];
    const float* Wout = (const float*)d_in[6];
    float* out = (float*)d_out;

    char* ws = (char*)d_ws;
    _Float16* Wkf   = (_Float16*)(ws);                // 524288 B
    float* v        = (float*)(ws + 524288);          //   2048 B
    float* partial2 = (float*)(ws + 526336);          // 524288 B (2 classes x 65536)
    float* logits   = (float*)(ws + 1050624);         // 262144 B
    float* blocksum = (float*)(ws + 1312768);         //   1024 B

    hipLaunchKernelGGL(qproj_kernel,  dim3(32),       dim3(256), 0, stream, Q, Wq, bq, Wout, v);
    hipLaunchKernelGGL(wkfrag_kernel, dim3(128),      dim3(256), 0, stream, Wk, Wkf);
    hipLaunchKernelGGL(score_kernel,  dim3(NWG, 2),   dim3(512), 0, stream, Kmat, Wkf, bk, v, partial2);
    hipLaunchKernelGGL(expsum_kernel, dim3(256),      dim3(256), 0, stream, partial2, logits, blocksum);
    hipLaunchKernelGGL(norm_kernel,   dim3(256),      dim3(256), 0, stream, logits, blocksum, out);
}